// Round 17
// baseline (2207.179 us; speedup 1.0000x reference)
//
#include <hip/hip_runtime.h>
#include <cstdint>
#include <cstddef>

#define B_  2
#define S_  2048
#define D_  4096
#define QH_ 32
#define NH_ 8
#define HD_ 128
#define MROWS (B_ * S_)                      // 4096
#define NQKV  (QH_ * HD_ + 2 * NH_ * HD_)    // 6144
#define KOFF  (QH_ * HD_)                    // 4096
#define VOFF  (QH_ * HD_ + NH_ * HD_)        // 5120

typedef __attribute__((ext_vector_type(8))) short bf16x8;
typedef __attribute__((ext_vector_type(4))) float f32x4;

__device__ __forceinline__ unsigned short f2bf(float f) {
    unsigned int u = __float_as_uint(f);
    return (unsigned short)((u + 0x7FFFu + ((u >> 16) & 1u)) >> 16);
}
__device__ __forceinline__ float bf2f(unsigned short h) { return __uint_as_float(((unsigned int)h) << 16); }

__device__ __forceinline__ void gl2lds16(const void* g, void* l) {
    __builtin_amdgcn_global_load_lds(
        (const __attribute__((address_space(1))) void*)g,
        (__attribute__((address_space(3))) void*)l, 16, 0, 0);
}

// ---------------------------------------------------------------------------
// fp32 -> bf16 straight convert (x). 8 elems/thread.
// ---------------------------------------------------------------------------
__global__ __launch_bounds__(256)
void convert_bf16_kernel(const float* __restrict__ in, unsigned short* __restrict__ out)
{
    const size_t i = ((size_t)blockIdx.x * 256 + threadIdx.x) * 8;
    float4 a = *(const float4*)(in + i);
    float4 b = *(const float4*)(in + i + 4);
    uint4 o;
    o.x = (unsigned int)f2bf(a.x) | ((unsigned int)f2bf(a.y) << 16);
    o.y = (unsigned int)f2bf(a.z) | ((unsigned int)f2bf(a.w) << 16);
    o.z = (unsigned int)f2bf(b.x) | ((unsigned int)f2bf(b.y) << 16);
    o.w = (unsigned int)f2bf(b.z) | ((unsigned int)f2bf(b.w) << 16);
    *(uint4*)(out + i) = o;
}

// ---------------------------------------------------------------------------
// Tile transpose-convert: in fp32 [R][C] (slab z) -> out bf16 [C][R]
// ---------------------------------------------------------------------------
__global__ __launch_bounds__(256)
void transpose_conv_kernel(const float* __restrict__ in, unsigned short* __restrict__ out,
                           int R, int C)
{
    __shared__ unsigned short tile[64][72];
    const int t  = threadIdx.x;
    const int c0 = blockIdx.x * 64;
    const int r0 = blockIdx.y * 64;
    in  += (size_t)blockIdx.z * R * C;
    out += (size_t)blockIdx.z * R * C;
    {
        const int rr = t >> 4;
        const int cc = (t & 15) * 4;
        #pragma unroll
        for (int p = 0; p < 4; ++p) {
            float4 v = *(const float4*)(in + (size_t)(r0 + p * 16 + rr) * C + c0 + cc);
            unsigned int lo = (unsigned int)f2bf(v.x) | ((unsigned int)f2bf(v.y) << 16);
            unsigned int hi = (unsigned int)f2bf(v.z) | ((unsigned int)f2bf(v.w) << 16);
            *(uint2*)&tile[p * 16 + rr][cc] = make_uint2(lo, hi);
        }
    }
    __syncthreads();
    {
        const int j  = t >> 3;
        const int i8 = (t & 7) * 8;
        #pragma unroll
        for (int p = 0; p < 2; ++p) {
            unsigned short tmp[8];
            #pragma unroll
            for (int e = 0; e < 8; ++e) tmp[e] = tile[i8 + e][p * 32 + j];
            *(uint4*)(out + (size_t)(c0 + p * 32 + j) * R + r0 + i8) = *(uint4*)tmp;
        }
    }
}

// ---------------------------------------------------------------------------
// bf16 transpose of the V slab of qkv: -> vt[(b*8+kh)*128 + h][2048 s]
// ---------------------------------------------------------------------------
__global__ __launch_bounds__(256)
void transpose_v_kernel(const unsigned short* __restrict__ qkv, unsigned short* __restrict__ vt)
{
    __shared__ unsigned short tile[64][76];
    const int t  = threadIdx.x;
    const int z  = blockIdx.z;            // b*8+kh
    const int b  = z >> 3, kh = z & 7;
    const int h0 = blockIdx.x * 64;
    const int s0 = blockIdx.y * 64;
    const unsigned short* in = qkv + (size_t)(b * S_) * NQKV + VOFF + kh * HD_;
    unsigned short* outb = vt + (size_t)z * HD_ * S_;
    {
        const int rr = t >> 4;            // s-local
        const int cc = (t & 15) * 4;      // h-local
        #pragma unroll
        for (int p = 0; p < 4; ++p) {
            uint2 v = *(const uint2*)(in + (size_t)(s0 + p * 16 + rr) * NQKV + h0 + cc);
            *(uint2*)&tile[p * 16 + rr][cc] = v;
        }
    }
    __syncthreads();
    {
        const int j  = t >> 3;            // h-local 0..31
        const int i8 = (t & 7) * 8;       // s-local
        #pragma unroll
        for (int p = 0; p < 2; ++p) {
            unsigned short tmp[8];
            #pragma unroll
            for (int e = 0; e < 8; ++e) tmp[e] = tile[i8 + e][p * 32 + j];
            *(uint4*)(outb + (size_t)(h0 + p * 32 + j) * S_ + s0 + i8) = *(uint4*)tmp;
        }
    }
}

// ---------------------------------------------------------------------------
// 256x256 GEMM, BK=32, rotate swizzle (conflicts==0, r11-verified), N-frag
// remap + fused RoPE epilogue (native sin/cos, r12/r13).
// r17: buffer count templated.
//   NBUF=3 (96 KiB, 1 block/CU): r13-proven — 2-tile prefetch lead,
//     counted vmcnt(4) gate (never 0 in-loop).
//   NBUF=2 (64 KiB, 2 blocks/CU via launch_bounds(512,4)): 1-tile lead,
//     vmcnt(0) at boundary — the drain is covered by the co-resident
//     block's MFMA burst (m114/m97 overlap mechanism), and QKV's 384
//     blocks all fit the 512 slots (tail eliminated).
// WAR proof (both): staged buffer was last read in tile kt-1, which all
// waves finished before tile kt's boundary barrier.
// ---------------------------------------------------------------------------
template<int CF32, int ROPE, int NBUF>
__global__ __launch_bounds__(512, NBUF == 2 ? 4 : 2)
void gemm256_kernel(const unsigned short* __restrict__ A,
                    const unsigned short* __restrict__ Bt,
                    void* __restrict__ Cp, const int* __restrict__ positions,
                    int Nst, int K)
{
    __shared__ alignas(16) unsigned short lds[NBUF][2][256][32];  // 32 KiB per buf

    const int t = threadIdx.x, l = t & 63, w = t >> 6;
    const int gx  = gridDim.x;
    const int nwg = gx * gridDim.y;
    int lin = blockIdx.y * gx + blockIdx.x;
    lin = (lin & 7) * (nwg >> 3) + (lin >> 3);       // bijective XCD swizzle (nwg%8==0)
    const int bn = (lin % gx) * 256, bm = (lin / gx) * 256;
    const int wr = w >> 2, wc = w & 3;               // 2 (M) x 4 (N) waves
    const int lm = l & 15, lg = l >> 4;

    f32x4 acc[8][4];
    #pragma unroll
    for (int i = 0; i < 8; ++i)
        #pragma unroll
        for (int j = 0; j < 4; ++j) acc[i][j] = (f32x4){0.f, 0.f, 0.f, 0.f};

    const int srow = w * 16 + (l >> 2);
    const int scol = (((l & 3) - ((l >> 3) & 3)) & 3) * 8;   // swizzled global col (elems)
    const unsigned short* Asrc = A  + (size_t)(bm + srow) * K + scol;
    const unsigned short* Bsrc = Bt + (size_t)(bn + srow) * K + scol;

    const int rcol = ((lg + ((lm >> 1) & 3)) & 3) * 8;       // swizzled read col

    #define STAGE_A(tt, bb) do {                                                  \
        gl2lds16(Asrc + (size_t)(tt) * 32,                  &lds[bb][0][w*16][0]); \
        gl2lds16(Asrc + (size_t)128*K + (size_t)(tt) * 32,  &lds[bb][0][128 + w*16][0]); } while (0)
    #define STAGE_B(tt, bb) do {                                                  \
        gl2lds16(Bsrc + (size_t)(tt) * 32,                  &lds[bb][1][w*16][0]); \
        gl2lds16(Bsrc + (size_t)128*K + (size_t)(tt) * 32,  &lds[bb][1][128 + w*16][0]); } while (0)

    const int nkt = K >> 5;
    STAGE_A(0, 0); STAGE_B(0, 0);
    if constexpr (NBUF == 3) { STAGE_A(1, 1); STAGE_B(1, 1); }

    for (int kt = 0; kt < nkt; ++kt) {
        if constexpr (NBUF == 3) {
            if (kt + 1 < nkt) asm volatile("s_waitcnt vmcnt(4)" ::: "memory");
            else              asm volatile("s_waitcnt vmcnt(0)" ::: "memory");
        } else {
            asm volatile("s_waitcnt vmcnt(0)" ::: "memory");
        }
        asm volatile("s_barrier" ::: "memory");

        const int cb = (NBUF == 3) ? (kt % 3) : (kt & 1);
        const int nb = (NBUF == 3) ? ((kt + 2) % 3) : ((kt + 1) & 1);
        const int pt = (NBUF == 3) ? (kt + 2) : (kt + 1);
        const bool pf = (pt < nkt);
        const unsigned short (*bufA)[32] = lds[cb][0];
        const unsigned short (*bufB)[32] = lds[cb][1];

        bf16x8 bfr[4], afr[4];
        #pragma unroll
        for (int j = 0; j < 4; ++j) bfr[j] = *(const bf16x8*)&bufB[j * 64 + wc * 16 + lm][rcol];
        #pragma unroll
        for (int i = 0; i < 4; ++i) afr[i] = *(const bf16x8*)&bufA[wr * 128 + i * 16 + lm][rcol];
        if (pf) STAGE_A(pt, nb);
        #pragma unroll
        for (int i = 0; i < 4; ++i)
            #pragma unroll
            for (int j = 0; j < 4; ++j)
                acc[i][j] = __builtin_amdgcn_mfma_f32_16x16x32_bf16(afr[i], bfr[j], acc[i][j], 0, 0, 0);

        #pragma unroll
        for (int i = 0; i < 4; ++i) afr[i] = *(const bf16x8*)&bufA[wr * 128 + (i + 4) * 16 + lm][rcol];
        if (pf) STAGE_B(pt, nb);
        #pragma unroll
        for (int i = 0; i < 4; ++i)
            #pragma unroll
            for (int j = 0; j < 4; ++j)
                acc[i + 4][j] = __builtin_amdgcn_mfma_f32_16x16x32_bf16(afr[i], bfr[j], acc[i + 4][j], 0, 0, 0);
    }
    #undef STAGE_A
    #undef STAGE_B

    // C/D: col = lane&15 within frag, row = (lane>>4)*4 + reg.
    // Frag j -> col bn + j*64 + wc*16 + lm. RoPE: pairs (j, j+1), j even.
    const int lr4 = lg * 4;
    float invf = 0.f;
    if constexpr (ROPE) {
        const int fi = wc * 16 + lm;                 // 0..63, j-independent
        invf = expf(-0.14391156831f * (float)fi);    // 10000^(-fi/64)
    }
    #pragma unroll
    for (int i = 0; i < 8; ++i) {
        #pragma unroll
        for (int jj = 0; jj < 4; ++jj) {
            const int row = bm + wr * 128 + i * 16 + lr4 + jj;
            float sn = 0.f, cs = 1.f;
            if constexpr (ROPE) {
                const float ang = (float)positions[row] * invf;
                sn = __sinf(ang);                    // native v_sin path
                cs = __cosf(ang);                    // native v_cos path
            }
            #pragma unroll
            for (int j = 0; j < 4; j += 2) {
                float x1 = acc[i][j][jj];
                float x2 = acc[i][j + 1][jj];
                const int col = bn + j * 64 + wc * 16 + lm;
                if constexpr (ROPE) {
                    if (col < VOFF) {                // Q/K heads only; V untouched
                        const float o1 = x1 * cs - x2 * sn;
                        const float o2 = x2 * cs + x1 * sn;
                        x1 = o1; x2 = o2;
                    }
                }
                if constexpr (CF32) {
                    ((float*)Cp)[(size_t)row * Nst + col]      = x1;
                    ((float*)Cp)[(size_t)row * Nst + col + 64] = x2;
                } else {
                    ((unsigned short*)Cp)[(size_t)row * Nst + col]      = f2bf(x1);
                    ((unsigned short*)Cp)[(size_t)row * Nst + col + 64] = f2bf(x2);
                }
            }
        }
    }
}

// ---------------------------------------------------------------------------
// MFMA flash attention, swapped-QK^T in-register softmax, gl2lds-staged K/V
// with rotate swizzle + double buffer (round-10/11, passing).
// ---------------------------------------------------------------------------
__global__ __launch_bounds__(256)
void attn_kernel(const unsigned short* __restrict__ qkv,
                 const unsigned short* __restrict__ vt,
                 unsigned short* __restrict__ ao)
{
    __shared__ alignas(16) unsigned short k_s[2][64][128];   // 32 KiB
    __shared__ alignas(16) unsigned short v_t[2][128][64];   // 32 KiB
    __shared__ alignas(16) unsigned short p_s[4][16][72];    // 9 KiB

    const int t   = threadIdx.x;
    const int blk = blockIdx.x;
    const int sb  = 31 - (blk >> 6);     // heavy (sb=31) blocks launch first
    const int pr  = blk & 63;
    const int qh  = pr >> 1;
    const int b   = pr & 1;
    const int kh  = qh >> 2;
    const int l   = t & 63, w = t >> 6;
    const int lm  = l & 15;
    const int lg  = l >> 4;
    const int lg4 = lg * 4;
    const int lko = lg * 8;
    const int wrow = w * 16 + lm;
    const int rot  = (lm & 7) * 8;       // read-side rotation (elems)

    const unsigned short* vtb = vt + (size_t)(b * NH_ + kh) * HD_ * S_;
    const size_t kvrow0 = (size_t)(b * S_) * NQKV + KOFF + kh * HD_;

    int ck[4], cv[2];
    #pragma unroll
    for (int kk = 0; kk < 4; ++kk) ck[kk] = (kk * 32 + lko - rot) & 127;
    #pragma unroll
    for (int kk = 0; kk < 2; ++kk) cv[kk] = (kk * 32 + lko - rot) & 63;

    const int krsub = l >> 4, ksseg = (l & 15) * 8;
    const int vrsub = l >> 3, vsseg = (l & 7) * 8;
    #define STAGEKV(cc, bb) do {                                                   \
        const int c64_ = (cc) * 64;                                                \
        _Pragma("unroll")                                                          \
        for (int i_ = 0; i_ < 4; ++i_) {                                           \
            const int kr_ = w * 16 + i_ * 4 + krsub;                               \
            const int ko_ = (ksseg + ((kr_ & 7) << 3)) & 127;                      \
            gl2lds16(qkv + kvrow0 + (size_t)(c64_ + kr_) * NQKV + ko_,             \
                     &k_s[bb][w * 16 + i_ * 4][0]);                                \
        }                                                                          \
        _Pragma("unroll")                                                          \
        for (int i_ = 0; i_ < 4; ++i_) {                                           \
            const int hv_ = w * 32 + i_ * 8 + vrsub;                               \
            const int vo_ = (vsseg + ((hv_ & 7) << 3)) & 63;                       \
            gl2lds16(vtb + (size_t)hv_ * S_ + c64_ + vo_,                          \
                     &v_t[bb][w * 32 + i_ * 8][0]);                                \
        }                                                                          \
    } while (0)

    bf16x8 qf[4];
    {
        const size_t qrow = (size_t)(b * S_ + sb * 64 + wrow) * NQKV + qh * HD_;
        #pragma unroll
        for (int kk = 0; kk < 4; ++kk)
            qf[kk] = *(const bf16x8*)(qkv + qrow + kk * 32 + lko);
    }

    f32x4 acc_o[8];
    #pragma unroll
    for (int i = 0; i < 8; ++i) acc_o[i] = (f32x4){0.f, 0.f, 0.f, 0.f};
    float mreg = -1e30f, lreg = 0.f;

    const float sm_scale = 0.08838834764831845f;

    STAGEKV(0, 0);

    for (int c = 0; c <= sb; ++c) {
        const int cur = c & 1;
        __syncthreads();
        if (c < sb) STAGEKV(c + 1, cur ^ 1);

        f32x4 acc_s[4];
        #pragma unroll
        for (int t4 = 0; t4 < 4; ++t4) acc_s[t4] = (f32x4){0.f, 0.f, 0.f, 0.f};
        #pragma unroll
        for (int kk = 0; kk < 4; ++kk) {
            const bf16x8 qv = qf[kk];
            bf16x8 kf0 = *(const bf16x8*)&k_s[cur][0 * 16 + lm][ck[kk]];
            bf16x8 kf1 = *(const bf16x8*)&k_s[cur][1 * 16 + lm][ck[kk]];
            bf16x8 kf2 = *(const bf16x8*)&k_s[cur][2 * 16 + lm][ck[kk]];
            bf16x8 kf3 = *(const bf16x8*)&k_s[cur][3 * 16 + lm][ck[kk]];
            __builtin_amdgcn_s_setprio(1);
            acc_s[0] = __builtin_amdgcn_mfma_f32_16x16x32_bf16(kf0, qv, acc_s[0], 0, 0, 0);
            acc_s[1] = __builtin_amdgcn_mfma_f32_16x16x32_bf16(kf1, qv, acc_s[1], 0, 0, 0);
            acc_s[2] = __builtin_amdgcn_mfma_f32_16x16x32_bf16(kf2, qv, acc_s[2], 0, 0, 0);
            acc_s[3] = __builtin_amdgcn_mfma_f32_16x16x32_bf16(kf3, qv, acc_s[3], 0, 0, 0);
            __builtin_amdgcn_s_setprio(0);
        }

        const bool diag = (c == sb);
        float p[4][4];
        #pragma unroll
        for (int t4 = 0; t4 < 4; ++t4)
            #pragma unroll
            for (int r = 0; r < 4; ++r) {
                float s = acc_s[t4][r] * sm_scale;
                if (diag && (t4 * 16 + lg4 + r > wrow)) s = -1e30f;
                p[t4][r] = s;
            }
        float mc = p[0][0];
        #pragma unroll
        for (int t4 = 0; t4 < 4; ++t4)
            #pragma unroll
            for (int r = 0; r < 4; ++r) mc = fmaxf(mc, p[t4][r]);
        mc = fmaxf(mc, __shfl_xor(mc, 16, 64));
        mc = fmaxf(mc, __shfl_xor(mc, 32, 64));
        float sf = 1.0f;
        if (mc > mreg + 8.0f) {
            sf = __expf(mreg - mc);
            mreg = mc;
            lreg *= sf;
        }
        if (__any(sf != 1.0f)) {
            #pragma unroll
            for (int r = 0; r < 4; ++r) {
                const float s_r = __shfl(sf, (l & 48) | (lg4 + r), 64);
                #pragma unroll
                for (int ht = 0; ht < 8; ++ht) acc_o[ht][r] *= s_r;
            }
        }
        float ps = 0.f;
        #pragma unroll
        for (int t4 = 0; t4 < 4; ++t4)
            #pragma unroll
            for (int r = 0; r < 4; ++r) {
                p[t4][r] = __expf(p[t4][r] - mreg);
                ps += p[t4][r];
            }
        ps += __shfl_xor(ps, 16, 64);
        ps += __shfl_xor(ps, 32, 64);
        lreg += ps;
        #pragma unroll
        for (int t4 = 0; t4 < 4; ++t4) {
            unsigned int d0 = (unsigned int)f2bf(p[t4][0]) | ((unsigned int)f2bf(p[t4][1]) << 16);
            unsigned int d1 = (unsigned int)f2bf(p[t4][2]) | ((unsigned int)f2bf(p[t4][3]) << 16);
            *(unsigned int*)&p_s[w][lm][t4 * 16 + lg4]     = d0;
            *(unsigned int*)&p_s[w][lm][t4 * 16 + lg4 + 2] = d1;
        }

        #pragma unroll
        for (int kk = 0; kk < 2; ++kk) {
            const bf16x8 pa = *(const bf16x8*)&p_s[w][lm][kk * 32 + lko];
            #pragma unroll
            for (int ht = 0; ht < 8; ht += 4) {
                bf16x8 bv0 = *(const bf16x8*)&v_t[cur][(ht + 0) * 16 + lm][cv[kk]];
                bf16x8 bv1 = *(const bf16x8*)&v_t[cur][(ht + 1) * 16 + lm][cv[kk]];
                bf16x8 bv2 = *(const bf16x8*)&v_t[cur][(ht + 2) * 16 + lm][cv[kk]];
                bf16x8 bv3 = *(const bf16x8*)&v_t[cur][(ht + 3) * 16 + lm][cv[kk]];
                __builtin_amdgcn_s_setprio(1);
                acc_o[ht + 0] = __builtin_amdgcn_mfma_f32_16x16x32_bf16(pa, bv0, acc_o[ht + 0], 0, 0, 0);
                acc_o[ht + 1] = __builtin_amdgcn_mfma_f32_16x16x32_bf16(pa, bv1, acc_o[ht + 1], 0, 0, 0);
                acc_o[ht + 2] = __builtin_amdgcn_mfma_f32_16x16x32_bf16(pa, bv2, acc_o[ht + 2], 0, 0, 0);
                acc_o[ht + 3] = __builtin_amdgcn_mfma_f32_16x16x32_bf16(pa, bv3, acc_o[ht + 3], 0, 0, 0);
                __builtin_amdgcn_s_setprio(0);
            }
        }
    }
    #undef STAGEKV

    #pragma unroll
    for (int r = 0; r < 4; ++r) {
        const float lr = __shfl(lreg, (l & 48) | (lg4 + r), 64);
        const float invl = 1.f / lr;
        const size_t row = (size_t)(b * S_ + sb * 64 + w * 16 + lg4 + r);
        #pragma unroll
        for (int ht = 0; ht < 8; ++ht)
            ao[(row * QH_ + qh) * HD_ + ht * 16 + lm] = f2bf(acc_o[ht][r] * invl);
    }
}

// ---------------------------------------------------------------------------
extern "C" void kernel_launch(void* const* d_in, const int* in_sizes, int n_in,
                              void* d_out, int out_size, void* d_ws, size_t ws_size,
                              hipStream_t stream)
{
    const float* x  = (const float*)d_in[0];
    const int*  pos = (const int*)d_in[1];
    const float* Wq = (const float*)d_in[2];
    const float* Wk = (const float*)d_in[3];
    const float* Wv = (const float*)d_in[4];
    const float* Wo = (const float*)d_in[5];
    float* out = (float*)d_out;

    char* wsb = (char*)d_ws;
    unsigned short* qkv = (unsigned short*)(wsb);              // 48 MiB [4096][6144]
    unsigned short* wt  = (unsigned short*)(wsb + 50331648);   // Wt_qkv 48M -> Wt_o 32M
    unsigned short* vt  = (unsigned short*)(wsb + 83886080);   // V^T
    unsigned short* r0  = (unsigned short*)(wsb + 100663296);  // 32 MiB x_bf -> ao

    const dim3 blk(256);
    const dim3 blk512(512);
    convert_bf16_kernel<<<8192, blk, 0, stream>>>(x, r0);
    transpose_conv_kernel<<<dim3(2, 64, 32), blk, 0, stream>>>(Wq, wt, D_, HD_);
    transpose_conv_kernel<<<dim3(2, 64, 8),  blk, 0, stream>>>(Wk, wt + (size_t)KOFF * D_, D_, HD_);
    transpose_conv_kernel<<<dim3(2, 64, 8),  blk, 0, stream>>>(Wv, wt + (size_t)VOFF * D_, D_, HD_);
    // fused QKV projection + RoPE; NBUF=2 -> 64 KiB LDS, 2 blocks/CU, no tail
    gemm256_kernel<0, 1, 2><<<dim3(NQKV / 256, MROWS / 256), blk512, 0, stream>>>(
        r0, wt, qkv, pos, NQKV, D_);
    transpose_conv_kernel<<<dim3(64, 64, 1), blk, 0, stream>>>(Wo, wt, D_, D_);
    transpose_v_kernel<<<dim3(2, 32, 16), blk, 0, stream>>>(qkv, vt);
    attn_kernel<<<B_ * QH_ * (S_ / 64), blk, 0, stream>>>(qkv, vt, r0);
    // output projection -> fp32 out; NBUF=3 (256 blocks = 1/CU, proven)
    gemm256_kernel<1, 0, 3><<<dim3(D_ / 256, MROWS / 256), blk512, 0, stream>>>(
        r0, wt, out, pos, D_, QH_ * HD_);
}

// Round 18
// 545.666 us; speedup vs baseline: 4.0449x; 4.0449x over previous
//
#include <hip/hip_runtime.h>
#include <cstdint>
#include <cstddef>

#define B_  2
#define S_  2048
#define D_  4096
#define QH_ 32
#define NH_ 8
#define HD_ 128
#define MROWS (B_ * S_)                      // 4096
#define NQKV  (QH_ * HD_ + 2 * NH_ * HD_)    // 6144
#define KOFF  (QH_ * HD_)                    // 4096
#define VOFF  (QH_ * HD_ + NH_ * HD_)        // 5120

typedef __attribute__((ext_vector_type(8))) short bf16x8;
typedef __attribute__((ext_vector_type(4))) float f32x4;

__device__ __forceinline__ unsigned short f2bf(float f) {
    unsigned int u = __float_as_uint(f);
    return (unsigned short)((u + 0x7FFFu + ((u >> 16) & 1u)) >> 16);
}
__device__ __forceinline__ float bf2f(unsigned short h) { return __uint_as_float(((unsigned int)h) << 16); }

__device__ __forceinline__ void gl2lds16(const void* g, void* l) {
    __builtin_amdgcn_global_load_lds(
        (const __attribute__((address_space(1))) void*)g,
        (__attribute__((address_space(3))) void*)l, 16, 0, 0);
}

// ---------------------------------------------------------------------------
// fp32 -> bf16 straight convert (x). 8 elems/thread.
// ---------------------------------------------------------------------------
__global__ __launch_bounds__(256)
void convert_bf16_kernel(const float* __restrict__ in, unsigned short* __restrict__ out)
{
    const size_t i = ((size_t)blockIdx.x * 256 + threadIdx.x) * 8;
    float4 a = *(const float4*)(in + i);
    float4 b = *(const float4*)(in + i + 4);
    uint4 o;
    o.x = (unsigned int)f2bf(a.x) | ((unsigned int)f2bf(a.y) << 16);
    o.y = (unsigned int)f2bf(a.z) | ((unsigned int)f2bf(a.w) << 16);
    o.z = (unsigned int)f2bf(b.x) | ((unsigned int)f2bf(b.y) << 16);
    o.w = (unsigned int)f2bf(b.z) | ((unsigned int)f2bf(b.w) << 16);
    *(uint4*)(out + i) = o;
}

// ---------------------------------------------------------------------------
// Tile transpose-convert: in fp32 [R][C] (slab z) -> out bf16 [C][R]
// ---------------------------------------------------------------------------
__global__ __launch_bounds__(256)
void transpose_conv_kernel(const float* __restrict__ in, unsigned short* __restrict__ out,
                           int R, int C)
{
    __shared__ unsigned short tile[64][72];
    const int t  = threadIdx.x;
    const int c0 = blockIdx.x * 64;
    const int r0 = blockIdx.y * 64;
    in  += (size_t)blockIdx.z * R * C;
    out += (size_t)blockIdx.z * R * C;
    {
        const int rr = t >> 4;
        const int cc = (t & 15) * 4;
        #pragma unroll
        for (int p = 0; p < 4; ++p) {
            float4 v = *(const float4*)(in + (size_t)(r0 + p * 16 + rr) * C + c0 + cc);
            unsigned int lo = (unsigned int)f2bf(v.x) | ((unsigned int)f2bf(v.y) << 16);
            unsigned int hi = (unsigned int)f2bf(v.z) | ((unsigned int)f2bf(v.w) << 16);
            *(uint2*)&tile[p * 16 + rr][cc] = make_uint2(lo, hi);
        }
    }
    __syncthreads();
    {
        const int j  = t >> 3;
        const int i8 = (t & 7) * 8;
        #pragma unroll
        for (int p = 0; p < 2; ++p) {
            unsigned short tmp[8];
            #pragma unroll
            for (int e = 0; e < 8; ++e) tmp[e] = tile[i8 + e][p * 32 + j];
            *(uint4*)(out + (size_t)(c0 + p * 32 + j) * R + r0 + i8) = *(uint4*)tmp;
        }
    }
}

// ---------------------------------------------------------------------------
// bf16 transpose of the V slab of qkv: -> vt[(b*8+kh)*128 + h][2048 s]
// ---------------------------------------------------------------------------
__global__ __launch_bounds__(256)
void transpose_v_kernel(const unsigned short* __restrict__ qkv, unsigned short* __restrict__ vt)
{
    __shared__ unsigned short tile[64][76];
    const int t  = threadIdx.x;
    const int z  = blockIdx.z;            // b*8+kh
    const int b  = z >> 3, kh = z & 7;
    const int h0 = blockIdx.x * 64;
    const int s0 = blockIdx.y * 64;
    const unsigned short* in = qkv + (size_t)(b * S_) * NQKV + VOFF + kh * HD_;
    unsigned short* outb = vt + (size_t)z * HD_ * S_;
    {
        const int rr = t >> 4;            // s-local
        const int cc = (t & 15) * 4;      // h-local
        #pragma unroll
        for (int p = 0; p < 4; ++p) {
            uint2 v = *(const uint2*)(in + (size_t)(s0 + p * 16 + rr) * NQKV + h0 + cc);
            *(uint2*)&tile[p * 16 + rr][cc] = v;
        }
    }
    __syncthreads();
    {
        const int j  = t >> 3;            // h-local 0..31
        const int i8 = (t & 7) * 8;       // s-local
        #pragma unroll
        for (int p = 0; p < 2; ++p) {
            unsigned short tmp[8];
            #pragma unroll
            for (int e = 0; e < 8; ++e) tmp[e] = tile[i8 + e][p * 32 + j];
            *(uint4*)(outb + (size_t)(h0 + p * 32 + j) * S_ + s0 + i8) = *(uint4*)tmp;
        }
    }
}

// ---------------------------------------------------------------------------
// 256x256 GEMM, BK=32, triple-buffered (96 KiB), ONE barrier + ONE counted
// vmcnt(4) gate per K-tile; tile kt+2 staged inside kt; rotate swizzle
// (conflicts == 0, r11-verified); N-frag remap + fused RoPE epilogue with
// native __sinf/__cosf (r12/r13). Best-measured configuration (545-546 us).
// r17 falsified occupancy trade: 2 blocks/CU needs VGPR<=128; acc alone is
// 128 -> spills (3 GB fetch). This config is the structural optimum.
// ---------------------------------------------------------------------------
template<int CF32, int ROPE>
__global__ __launch_bounds__(512, 2)
void gemm256_kernel(const unsigned short* __restrict__ A,
                    const unsigned short* __restrict__ Bt,
                    void* __restrict__ Cp, const int* __restrict__ positions,
                    int Nst, int K)
{
    __shared__ alignas(16) unsigned short lds[3][2][256][32];  // 96 KiB

    const int t = threadIdx.x, l = t & 63, w = t >> 6;
    const int gx  = gridDim.x;
    const int nwg = gx * gridDim.y;
    int lin = blockIdx.y * gx + blockIdx.x;
    lin = (lin & 7) * (nwg >> 3) + (lin >> 3);       // bijective XCD swizzle (nwg%8==0)
    const int bn = (lin % gx) * 256, bm = (lin / gx) * 256;
    const int wr = w >> 2, wc = w & 3;               // 2 (M) x 4 (N) waves
    const int lm = l & 15, lg = l >> 4;

    f32x4 acc[8][4];
    #pragma unroll
    for (int i = 0; i < 8; ++i)
        #pragma unroll
        for (int j = 0; j < 4; ++j) acc[i][j] = (f32x4){0.f, 0.f, 0.f, 0.f};

    const int srow = w * 16 + (l >> 2);
    const int scol = (((l & 3) - ((l >> 3) & 3)) & 3) * 8;   // swizzled global col (elems)
    const unsigned short* Asrc = A  + (size_t)(bm + srow) * K + scol;
    const unsigned short* Bsrc = Bt + (size_t)(bn + srow) * K + scol;

    const int rcol = ((lg + ((lm >> 1) & 3)) & 3) * 8;       // swizzled read col

    #define STAGE_A(tt, bb) do {                                                  \
        gl2lds16(Asrc + (size_t)(tt) * 32,                  &lds[bb][0][w*16][0]); \
        gl2lds16(Asrc + (size_t)128*K + (size_t)(tt) * 32,  &lds[bb][0][128 + w*16][0]); } while (0)
    #define STAGE_B(tt, bb) do {                                                  \
        gl2lds16(Bsrc + (size_t)(tt) * 32,                  &lds[bb][1][w*16][0]); \
        gl2lds16(Bsrc + (size_t)128*K + (size_t)(tt) * 32,  &lds[bb][1][128 + w*16][0]); } while (0)

    const int nkt = K >> 5;
    STAGE_A(0, 0); STAGE_B(0, 0);
    STAGE_A(1, 1); STAGE_B(1, 1);

    for (int kt = 0; kt < nkt; ++kt) {
        if (kt + 1 < nkt) asm volatile("s_waitcnt vmcnt(4)" ::: "memory");
        else              asm volatile("s_waitcnt vmcnt(0)" ::: "memory");
        asm volatile("s_barrier" ::: "memory");

        const unsigned short (*bufA)[32] = lds[kt % 3][0];
        const unsigned short (*bufB)[32] = lds[kt % 3][1];
        const int nb = (kt + 2) % 3;
        const bool pf = (kt + 2 < nkt);

        bf16x8 bfr[4], afr[4];
        #pragma unroll
        for (int j = 0; j < 4; ++j) bfr[j] = *(const bf16x8*)&bufB[j * 64 + wc * 16 + lm][rcol];
        #pragma unroll
        for (int i = 0; i < 4; ++i) afr[i] = *(const bf16x8*)&bufA[wr * 128 + i * 16 + lm][rcol];
        if (pf) STAGE_A(kt + 2, nb);
        #pragma unroll
        for (int i = 0; i < 4; ++i)
            #pragma unroll
            for (int j = 0; j < 4; ++j)
                acc[i][j] = __builtin_amdgcn_mfma_f32_16x16x32_bf16(afr[i], bfr[j], acc[i][j], 0, 0, 0);

        #pragma unroll
        for (int i = 0; i < 4; ++i) afr[i] = *(const bf16x8*)&bufA[wr * 128 + (i + 4) * 16 + lm][rcol];
        if (pf) STAGE_B(kt + 2, nb);
        #pragma unroll
        for (int i = 0; i < 4; ++i)
            #pragma unroll
            for (int j = 0; j < 4; ++j)
                acc[i + 4][j] = __builtin_amdgcn_mfma_f32_16x16x32_bf16(afr[i], bfr[j], acc[i + 4][j], 0, 0, 0);
    }
    #undef STAGE_A
    #undef STAGE_B

    // C/D: col = lane&15 within frag, row = (lane>>4)*4 + reg.
    // Frag j -> col bn + j*64 + wc*16 + lm. RoPE: pairs (j, j+1), j even.
    const int lr4 = lg * 4;
    float invf = 0.f;
    if constexpr (ROPE) {
        const int fi = wc * 16 + lm;                 // 0..63, j-independent
        invf = expf(-0.14391156831f * (float)fi);    // 10000^(-fi/64)
    }
    #pragma unroll
    for (int i = 0; i < 8; ++i) {
        #pragma unroll
        for (int jj = 0; jj < 4; ++jj) {
            const int row = bm + wr * 128 + i * 16 + lr4 + jj;
            float sn = 0.f, cs = 1.f;
            if constexpr (ROPE) {
                const float ang = (float)positions[row] * invf;
                sn = __sinf(ang);                    // native v_sin path
                cs = __cosf(ang);                    // native v_cos path
            }
            #pragma unroll
            for (int j = 0; j < 4; j += 2) {
                float x1 = acc[i][j][jj];
                float x2 = acc[i][j + 1][jj];
                const int col = bn + j * 64 + wc * 16 + lm;
                if constexpr (ROPE) {
                    if (col < VOFF) {                // Q/K heads only; V untouched
                        const float o1 = x1 * cs - x2 * sn;
                        const float o2 = x2 * cs + x1 * sn;
                        x1 = o1; x2 = o2;
                    }
                }
                if constexpr (CF32) {
                    ((float*)Cp)[(size_t)row * Nst + col]      = x1;
                    ((float*)Cp)[(size_t)row * Nst + col + 64] = x2;
                } else {
                    ((unsigned short*)Cp)[(size_t)row * Nst + col]      = f2bf(x1);
                    ((unsigned short*)Cp)[(size_t)row * Nst + col + 64] = f2bf(x2);
                }
            }
        }
    }
}

// ---------------------------------------------------------------------------
// MFMA flash attention, swapped-QK^T in-register softmax, gl2lds-staged K/V
// with rotate swizzle + double buffer (round-10/11, passing).
// ---------------------------------------------------------------------------
__global__ __launch_bounds__(256)
void attn_kernel(const unsigned short* __restrict__ qkv,
                 const unsigned short* __restrict__ vt,
                 unsigned short* __restrict__ ao)
{
    __shared__ alignas(16) unsigned short k_s[2][64][128];   // 32 KiB
    __shared__ alignas(16) unsigned short v_t[2][128][64];   // 32 KiB
    __shared__ alignas(16) unsigned short p_s[4][16][72];    // 9 KiB

    const int t   = threadIdx.x;
    const int blk = blockIdx.x;
    const int sb  = 31 - (blk >> 6);     // heavy (sb=31) blocks launch first
    const int pr  = blk & 63;
    const int qh  = pr >> 1;
    const int b   = pr & 1;
    const int kh  = qh >> 2;
    const int l   = t & 63, w = t >> 6;
    const int lm  = l & 15;
    const int lg  = l >> 4;
    const int lg4 = lg * 4;
    const int lko = lg * 8;
    const int wrow = w * 16 + lm;
    const int rot  = (lm & 7) * 8;       // read-side rotation (elems)

    const unsigned short* vtb = vt + (size_t)(b * NH_ + kh) * HD_ * S_;
    const size_t kvrow0 = (size_t)(b * S_) * NQKV + KOFF + kh * HD_;

    int ck[4], cv[2];
    #pragma unroll
    for (int kk = 0; kk < 4; ++kk) ck[kk] = (kk * 32 + lko - rot) & 127;
    #pragma unroll
    for (int kk = 0; kk < 2; ++kk) cv[kk] = (kk * 32 + lko - rot) & 63;

    const int krsub = l >> 4, ksseg = (l & 15) * 8;
    const int vrsub = l >> 3, vsseg = (l & 7) * 8;
    #define STAGEKV(cc, bb) do {                                                   \
        const int c64_ = (cc) * 64;                                                \
        _Pragma("unroll")                                                          \
        for (int i_ = 0; i_ < 4; ++i_) {                                           \
            const int kr_ = w * 16 + i_ * 4 + krsub;                               \
            const int ko_ = (ksseg + ((kr_ & 7) << 3)) & 127;                      \
            gl2lds16(qkv + kvrow0 + (size_t)(c64_ + kr_) * NQKV + ko_,             \
                     &k_s[bb][w * 16 + i_ * 4][0]);                                \
        }                                                                          \
        _Pragma("unroll")                                                          \
        for (int i_ = 0; i_ < 4; ++i_) {                                           \
            const int hv_ = w * 32 + i_ * 8 + vrsub;                               \
            const int vo_ = (vsseg + ((hv_ & 7) << 3)) & 63;                       \
            gl2lds16(vtb + (size_t)hv_ * S_ + c64_ + vo_,                          \
                     &v_t[bb][w * 32 + i_ * 8][0]);                                \
        }                                                                          \
    } while (0)

    bf16x8 qf[4];
    {
        const size_t qrow = (size_t)(b * S_ + sb * 64 + wrow) * NQKV + qh * HD_;
        #pragma unroll
        for (int kk = 0; kk < 4; ++kk)
            qf[kk] = *(const bf16x8*)(qkv + qrow + kk * 32 + lko);
    }

    f32x4 acc_o[8];
    #pragma unroll
    for (int i = 0; i < 8; ++i) acc_o[i] = (f32x4){0.f, 0.f, 0.f, 0.f};
    float mreg = -1e30f, lreg = 0.f;

    const float sm_scale = 0.08838834764831845f;

    STAGEKV(0, 0);

    for (int c = 0; c <= sb; ++c) {
        const int cur = c & 1;
        __syncthreads();
        if (c < sb) STAGEKV(c + 1, cur ^ 1);

        f32x4 acc_s[4];
        #pragma unroll
        for (int t4 = 0; t4 < 4; ++t4) acc_s[t4] = (f32x4){0.f, 0.f, 0.f, 0.f};
        #pragma unroll
        for (int kk = 0; kk < 4; ++kk) {
            const bf16x8 qv = qf[kk];
            bf16x8 kf0 = *(const bf16x8*)&k_s[cur][0 * 16 + lm][ck[kk]];
            bf16x8 kf1 = *(const bf16x8*)&k_s[cur][1 * 16 + lm][ck[kk]];
            bf16x8 kf2 = *(const bf16x8*)&k_s[cur][2 * 16 + lm][ck[kk]];
            bf16x8 kf3 = *(const bf16x8*)&k_s[cur][3 * 16 + lm][ck[kk]];
            __builtin_amdgcn_s_setprio(1);
            acc_s[0] = __builtin_amdgcn_mfma_f32_16x16x32_bf16(kf0, qv, acc_s[0], 0, 0, 0);
            acc_s[1] = __builtin_amdgcn_mfma_f32_16x16x32_bf16(kf1, qv, acc_s[1], 0, 0, 0);
            acc_s[2] = __builtin_amdgcn_mfma_f32_16x16x32_bf16(kf2, qv, acc_s[2], 0, 0, 0);
            acc_s[3] = __builtin_amdgcn_mfma_f32_16x16x32_bf16(kf3, qv, acc_s[3], 0, 0, 0);
            __builtin_amdgcn_s_setprio(0);
        }

        const bool diag = (c == sb);
        float p[4][4];
        #pragma unroll
        for (int t4 = 0; t4 < 4; ++t4)
            #pragma unroll
            for (int r = 0; r < 4; ++r) {
                float s = acc_s[t4][r] * sm_scale;
                if (diag && (t4 * 16 + lg4 + r > wrow)) s = -1e30f;
                p[t4][r] = s;
            }
        float mc = p[0][0];
        #pragma unroll
        for (int t4 = 0; t4 < 4; ++t4)
            #pragma unroll
            for (int r = 0; r < 4; ++r) mc = fmaxf(mc, p[t4][r]);
        mc = fmaxf(mc, __shfl_xor(mc, 16, 64));
        mc = fmaxf(mc, __shfl_xor(mc, 32, 64));
        float sf = 1.0f;
        if (mc > mreg + 8.0f) {
            sf = __expf(mreg - mc);
            mreg = mc;
            lreg *= sf;
        }
        if (__any(sf != 1.0f)) {
            #pragma unroll
            for (int r = 0; r < 4; ++r) {
                const float s_r = __shfl(sf, (l & 48) | (lg4 + r), 64);
                #pragma unroll
                for (int ht = 0; ht < 8; ++ht) acc_o[ht][r] *= s_r;
            }
        }
        float ps = 0.f;
        #pragma unroll
        for (int t4 = 0; t4 < 4; ++t4)
            #pragma unroll
            for (int r = 0; r < 4; ++r) {
                p[t4][r] = __expf(p[t4][r] - mreg);
                ps += p[t4][r];
            }
        ps += __shfl_xor(ps, 16, 64);
        ps += __shfl_xor(ps, 32, 64);
        lreg += ps;
        #pragma unroll
        for (int t4 = 0; t4 < 4; ++t4) {
            unsigned int d0 = (unsigned int)f2bf(p[t4][0]) | ((unsigned int)f2bf(p[t4][1]) << 16);
            unsigned int d1 = (unsigned int)f2bf(p[t4][2]) | ((unsigned int)f2bf(p[t4][3]) << 16);
            *(unsigned int*)&p_s[w][lm][t4 * 16 + lg4]     = d0;
            *(unsigned int*)&p_s[w][lm][t4 * 16 + lg4 + 2] = d1;
        }

        #pragma unroll
        for (int kk = 0; kk < 2; ++kk) {
            const bf16x8 pa = *(const bf16x8*)&p_s[w][lm][kk * 32 + lko];
            #pragma unroll
            for (int ht = 0; ht < 8; ht += 4) {
                bf16x8 bv0 = *(const bf16x8*)&v_t[cur][(ht + 0) * 16 + lm][cv[kk]];
                bf16x8 bv1 = *(const bf16x8*)&v_t[cur][(ht + 1) * 16 + lm][cv[kk]];
                bf16x8 bv2 = *(const bf16x8*)&v_t[cur][(ht + 2) * 16 + lm][cv[kk]];
                bf16x8 bv3 = *(const bf16x8*)&v_t[cur][(ht + 3) * 16 + lm][cv[kk]];
                __builtin_amdgcn_s_setprio(1);
                acc_o[ht + 0] = __builtin_amdgcn_mfma_f32_16x16x32_bf16(pa, bv0, acc_o[ht + 0], 0, 0, 0);
                acc_o[ht + 1] = __builtin_amdgcn_mfma_f32_16x16x32_bf16(pa, bv1, acc_o[ht + 1], 0, 0, 0);
                acc_o[ht + 2] = __builtin_amdgcn_mfma_f32_16x16x32_bf16(pa, bv2, acc_o[ht + 2], 0, 0, 0);
                acc_o[ht + 3] = __builtin_amdgcn_mfma_f32_16x16x32_bf16(pa, bv3, acc_o[ht + 3], 0, 0, 0);
                __builtin_amdgcn_s_setprio(0);
            }
        }
    }
    #undef STAGEKV

    #pragma unroll
    for (int r = 0; r < 4; ++r) {
        const float lr = __shfl(lreg, (l & 48) | (lg4 + r), 64);
        const float invl = 1.f / lr;
        const size_t row = (size_t)(b * S_ + sb * 64 + w * 16 + lg4 + r);
        #pragma unroll
        for (int ht = 0; ht < 8; ++ht)
            ao[(row * QH_ + qh) * HD_ + ht * 16 + lm] = f2bf(acc_o[ht][r] * invl);
    }
}

// ---------------------------------------------------------------------------
extern "C" void kernel_launch(void* const* d_in, const int* in_sizes, int n_in,
                              void* d_out, int out_size, void* d_ws, size_t ws_size,
                              hipStream_t stream)
{
    const float* x  = (const float*)d_in[0];
    const int*  pos = (const int*)d_in[1];
    const float* Wq = (const float*)d_in[2];
    const float* Wk = (const float*)d_in[3];
    const float* Wv = (const float*)d_in[4];
    const float* Wo = (const float*)d_in[5];
    float* out = (float*)d_out;

    char* wsb = (char*)d_ws;
    unsigned short* qkv = (unsigned short*)(wsb);              // 48 MiB [4096][6144]
    unsigned short* wt  = (unsigned short*)(wsb + 50331648);   // Wt_qkv 48M -> Wt_o 32M
    unsigned short* vt  = (unsigned short*)(wsb + 83886080);   // V^T
    unsigned short* r0  = (unsigned short*)(wsb + 100663296);  // 32 MiB x_bf -> ao

    const dim3 blk(256);
    const dim3 blk512(512);
    convert_bf16_kernel<<<8192, blk, 0, stream>>>(x, r0);
    transpose_conv_kernel<<<dim3(2, 64, 32), blk, 0, stream>>>(Wq, wt, D_, HD_);
    transpose_conv_kernel<<<dim3(2, 64, 8),  blk, 0, stream>>>(Wk, wt + (size_t)KOFF * D_, D_, HD_);
    transpose_conv_kernel<<<dim3(2, 64, 8),  blk, 0, stream>>>(Wv, wt + (size_t)VOFF * D_, D_, HD_);
    // fused QKV projection + RoPE (applied to cols < VOFF in epilogue)
    gemm256_kernel<0, 1><<<dim3(NQKV / 256, MROWS / 256), blk512, 0, stream>>>(
        r0, wt, qkv, pos, NQKV, D_);
    transpose_conv_kernel<<<dim3(64, 64, 1), blk, 0, stream>>>(Wo, wt, D_, D_);
    transpose_v_kernel<<<dim3(2, 32, 16), blk, 0, stream>>>(qkv, vt);
    attn_kernel<<<B_ * QH_ * (S_ / 64), blk, 0, stream>>>(qkv, vt, r0);
    // output projection -> fp32 out
    gemm256_kernel<1, 0><<<dim3(D_ / 256, MROWS / 256), blk512, 0, stream>>>(
        r0, wt, out, pos, D_, QH_ * HD_);
}